// Round 2
// baseline (358.376 us; speedup 1.0000x reference)
//
#include <hip/hip_runtime.h>
#include <cstdint>
#include <cstddef>

// Problem constants (fixed by reference):
#define NSLOTS 16
#define DIM    256        // SLOT_DIM = FEAT_DIM = K = N of both GEMMs
#define FEAT   4096
#define MT     128        // rows per GEMM block tile
#define LDA    264        // Abuf row stride in bf16 elements (+8 pad)

typedef __attribute__((ext_vector_type(8))) short  short8;   // 8 bf16 bit-patterns (4 VGPRs)
typedef __attribute__((ext_vector_type(4))) float  floatx4;  // MFMA accumulator / float4

__device__ __forceinline__ short f2bf(float f) {
    unsigned u = __builtin_bit_cast(unsigned, f);
    u += 0x7FFFu + ((u >> 16) & 1u);
    return (short)(u >> 16);
}

// ---------------------------------------------------------------------------
// Kernel 1: swizzle W1/W2 (fp32 [K=256][N=256] row-major) into bf16 MFMA
// fragment order: Ws[((kt*16 + nt)*64 + lane)*8 + j] = W[kt*32 + (lane>>4)*8 + j][nt*16 + (lane&15)]
// This is simultaneously the B-operand layout for W and the A-operand layout
// for W^T (lane&15 indexes n, quad*8+j indexes k) — we use it as A-operand.
// ---------------------------------------------------------------------------
__global__ void swizzle_w_kernel(const float* __restrict__ W1,
                                 const float* __restrict__ W2,
                                 short* __restrict__ W1s,
                                 short* __restrict__ W2s) {
    int t = blockIdx.x * blockDim.x + threadIdx.x;   // 16384 threads total
    int lane = t & 63;
    int nt   = (t >> 6) & 15;
    int kt   = (t >> 10) & 7;
    int m    = t >> 13;
    const float* W  = m ? W2 : W1;
    short*       Ws = m ? W2s : W1s;
    int n  = nt * 16 + (lane & 15);
    int kb = kt * 32 + (lane >> 4) * 8;
    short* dst = Ws + ((size_t)((kt * 16 + nt) * 64 + lane)) * 8;
#pragma unroll
    for (int j = 0; j < 8; ++j)
        dst[j] = f2bf(W[(size_t)(kb + j) * DIM + n]);
}

// ---------------------------------------------------------------------------
// MFMA core, operand-swapped: D = W_frag (as A, = W^T) x h_frag (as B, = h^T)
// => D[n][m]: C/D row (quad*4+reg) = out COLUMN (4 consecutive), col (lane&15)
// = out ROW. 8 waves: wave w covers n-tiles {2w, 2w+1}, all 8 m-tiles.
// Per kt: 2 W-frag loads (reuse 8x), 8 h-frag ds_reads.
// ---------------------------------------------------------------------------
__device__ __forceinline__ void mfma_core(const short* Abuf,
                                          const short* __restrict__ Ws,
                                          int tid, floatx4 acc[8][2]) {
    int lane = tid & 63;
    int w    = tid >> 6;                 // n-group: tiles 2w, 2w+1
    int arow = lane & 15;
    int ak   = (lane >> 4) * 8;
#pragma unroll
    for (int kt = 0; kt < 8; ++kt) {
        short8 wv[2], a[8];
#pragma unroll
        for (int nt = 0; nt < 2; ++nt)
            wv[nt] = *(const short8*)(Ws + ((size_t)((kt * 16 + w * 2 + nt) * 64 + lane)) * 8);
#pragma unroll
        for (int mt = 0; mt < 8; ++mt)
            a[mt] = *(const short8*)(Abuf + (mt * 16 + arow) * LDA + kt * 32 + ak);
#pragma unroll
        for (int mt = 0; mt < 8; ++mt)
#pragma unroll
            for (int nt = 0; nt < 2; ++nt)
                acc[mt][nt] = __builtin_amdgcn_mfma_f32_16x16x32_bf16(
                    wv[nt], a[mt], acc[mt][nt], 0, 0, 0);
    }
}

// Epilogue: lane holds out rows row0+mt*16+(lane&15), cols cb..cb+3 (float4)
__device__ __forceinline__ void store_epilogue(float* __restrict__ dst, size_t row0,
                                               const float* __restrict__ bias,
                                               int tid, floatx4 acc[8][2]) {
    int lane = tid & 63;
    int w    = tid >> 6;
    int l    = lane & 15;
    int q    = lane >> 4;
#pragma unroll
    for (int nt = 0; nt < 2; ++nt) {
        int cb = w * 32 + nt * 16 + q * 4;
        floatx4 bv = *(const floatx4*)(bias + cb);
#pragma unroll
        for (int mt = 0; mt < 8; ++mt) {
            floatx4 v = acc[mt][nt] + bv;
            *(floatx4*)(dst + (row0 + mt * 16 + l) * DIM + cb) = v;
        }
    }
}

// ---------------------------------------------------------------------------
// Kernel 2: precompute S1 = slots@W1 + b1 (rows 0..1023) and P1 = pos@W1
// (rows 1024..5119), fp32 into workspace. 40 blocks x 512 threads.
// ---------------------------------------------------------------------------
__global__ __launch_bounds__(512) void precompute_kernel(
        const float* __restrict__ slots, const float* __restrict__ pos,
        const float* __restrict__ b1, const short* __restrict__ W1s,
        float* __restrict__ S1P1) {
    __shared__ short Abuf[MT * LDA];
    __shared__ float zbias[DIM];
    int tid  = threadIdx.x;
    int row0 = blockIdx.x * MT;          // [0,5120); block is all-slots or all-pos
    bool isSlots = (row0 < 1024);
    if (tid < DIM) zbias[tid] = isSlots ? b1[tid] : 0.f;
#pragma unroll
    for (int p = 0; p < 8; ++p) {
        int v   = tid + p * 512;         // 0..4095 -> (row, k-octet)
        int row = v >> 5;
        int k0  = (v & 31) * 8;
        int gr  = row0 + row;
        const float* src = isSlots ? (slots + (size_t)gr * DIM + k0)
                                   : (pos + (size_t)(gr - 1024) * DIM + k0);
        short8 hv;
#pragma unroll
        for (int j = 0; j < 8; ++j) hv[j] = f2bf(src[j]);
        *(short8*)(Abuf + row * LDA + k0) = hv;
    }
    __syncthreads();

    floatx4 acc[8][2];
#pragma unroll
    for (int mt = 0; mt < 8; ++mt)
#pragma unroll
        for (int nt = 0; nt < 2; ++nt)
            acc[mt][nt] = floatx4{0.f, 0.f, 0.f, 0.f};
    mfma_core(Abuf, W1s, tid, acc);
    store_epilogue(S1P1, (size_t)row0, zbias, tid, acc);
}

// ---------------------------------------------------------------------------
// Kernel 3: fused main. Per 128-row tile (one b, 128 consecutive f):
//   argmax over 16 mask vals -> h = relu(S1[b,idx]+P1[f]) bf16 in LDS
//   -> MFMA vs W2 -> +b2 -> float4 stores.
// ---------------------------------------------------------------------------
__global__ __launch_bounds__(512) void fused_main_kernel(
        const float* __restrict__ mask, const float* __restrict__ b2,
        const float* __restrict__ S1P1, const short* __restrict__ W2s,
        float* __restrict__ out) {
    __shared__ short Abuf[MT * LDA];
    __shared__ float sVal[4][MT];
    __shared__ int   sArg[4][MT];
    __shared__ int   sIdx[MT];
    int tid  = threadIdx.x;
    int row0 = blockIdx.x * MT;          // global output row = b*4096 + f
    int b    = row0 >> 12;
    int f0   = row0 & (FEAT - 1);

    // parallel argmax: 4 partial scans per row (slot order preserved), then
    // ordered reduce -> exact first-max semantics (matches jnp.argmax)
    {
        int row  = tid & (MT - 1);
        int part = tid >> 7;             // 0..3, scans slots part*4..part*4+3
        const float* mp = mask + (size_t)b * NSLOTS * FEAT + (size_t)(part * 4) * FEAT + (f0 + row);
        float best = mp[0];
        int bi = part * 4;
#pragma unroll
        for (int s = 1; s < 4; ++s) {
            float v = mp[(size_t)s * FEAT];
            if (v > best) { best = v; bi = part * 4 + s; }
        }
        sVal[part][row] = best;
        sArg[part][row] = bi;
    }
    __syncthreads();
    if (tid < MT) {
        float best = sVal[0][tid];
        int bi = sArg[0][tid];
#pragma unroll
        for (int p = 1; p < 4; ++p) {
            float v = sVal[p][tid];
            if (v > best) { best = v; bi = sArg[p][tid]; }
        }
        sIdx[tid] = bi;
    }
    __syncthreads();

    // build h tile: relu(S1[b, idx[row]] + P1[f0+row]) -> bf16 into LDS
    const float* P1 = S1P1 + (size_t)1024 * DIM;
#pragma unroll
    for (int p = 0; p < 8; ++p) {
        int v   = tid + p * 512;
        int row = v >> 5;
        int k0  = (v & 31) * 8;
        int s   = sIdx[row];
        const floatx4* s1 = (const floatx4*)(S1P1 + ((size_t)(b * NSLOTS + s)) * DIM + k0);
        const floatx4* p1 = (const floatx4*)(P1 + (size_t)(f0 + row) * DIM + k0);
        floatx4 x0 = s1[0] + p1[0];
        floatx4 x1 = s1[1] + p1[1];
        short8 hv;
#pragma unroll
        for (int j = 0; j < 4; ++j) {
            hv[j]     = f2bf(fmaxf(x0[j], 0.f));
            hv[j + 4] = f2bf(fmaxf(x1[j], 0.f));
        }
        *(short8*)(Abuf + row * LDA + k0) = hv;
    }
    __syncthreads();

    floatx4 acc[8][2];
#pragma unroll
    for (int mt = 0; mt < 8; ++mt)
#pragma unroll
        for (int nt = 0; nt < 2; ++nt)
            acc[mt][nt] = floatx4{0.f, 0.f, 0.f, 0.f};
    mfma_core(Abuf, W2s, tid, acc);
    store_epilogue(out, (size_t)row0, b2, tid, acc);
}

// ---------------------------------------------------------------------------
extern "C" void kernel_launch(void* const* d_in, const int* in_sizes, int n_in,
                              void* d_out, int out_size, void* d_ws, size_t ws_size,
                              hipStream_t stream) {
    const float* slots = (const float*)d_in[0];  // [64,16,256]
    const float* mask  = (const float*)d_in[1];  // [64,16,4096]
    const float* pos   = (const float*)d_in[2];  // [1,4096,256]
    const float* W1    = (const float*)d_in[3];  // [256,256]
    const float* b1    = (const float*)d_in[4];  // [256]
    const float* W2    = (const float*)d_in[5];  // [256,256]
    const float* b2    = (const float*)d_in[6];  // [256]
    float* out = (float*)d_out;                  // [64,4096,256] fp32

    // workspace: S1P1 fp32 [5120*256] (5 MB) | W1s bf16 [64K] | W2s bf16 [64K]
    char* ws = (char*)d_ws;
    float* S1P1 = (float*)ws;
    short* W1s  = (short*)(ws + (size_t)5120 * 256 * 4);
    short* W2s  = W1s + 65536;

    swizzle_w_kernel<<<64, 256, 0, stream>>>(W1, W2, W1s, W2s);
    precompute_kernel<<<40, 512, 0, stream>>>(slots, pos, b1, W1s, S1P1);
    fused_main_kernel<<<2048, 512, 0, stream>>>(mask, b2, S1P1, W2s, out);
}